// Round 7
// baseline (171.762 us; speedup 1.0000x reference)
//
#include <hip/hip_runtime.h>
#include <hip/hip_bf16.h>
#include <cstddef>

// ---------------------------------------------------------------------------
// B=16, N=4, S=64, K=50, VD=1024, QD=768, H=512; ROWS = B*N*S = 4096
//   Ev[k_glob][h] = exp2(CEXP*(v[b,k,:] .Wv[h,:] + bv[h]))   (row-major)
//   Eq[row][h]    = exp2(CEXP*(q[row,:] .Wq[h,:] + bq[h]))
//   logit[row][k] = sum_h (-2*wl[h]) * rcp(Ev[k][h]*Eq[row][h] + 1)
//     (tanh(x) = 1 - 2/(e^{2x}+1); exp2 factorized into the projection
//      spaces; k-uniform sum_h wl dropped: softmax-invariant; CEXP=2*log2e)
//   out = masked softmax over k (50 boxes)
// ---------------------------------------------------------------------------

typedef __attribute__((ext_vector_type(2))) float        f32x2;
typedef __attribute__((ext_vector_type(4))) float        f32x4;
typedef __attribute__((ext_vector_type(8))) short        bfrag;   // 8 bf16
typedef __attribute__((ext_vector_type(4))) unsigned int u32x4;

#define LGKM0  asm volatile("s_waitcnt lgkmcnt(0)" ::: "memory")
#define SBAR   __builtin_amdgcn_s_barrier()
#define SCHED0 __builtin_amdgcn_sched_barrier(0)

__device__ __forceinline__ void gload4(const float* g, float* l) {
  __builtin_amdgcn_global_load_lds((const __attribute__((address_space(1))) void*)g,
                                   (__attribute__((address_space(3))) void*)l, 4, 0, 0);
}

__device__ __forceinline__ unsigned int cvtpk(float a, float b) {
  unsigned int r;
  asm("v_cvt_pk_bf16_f32 %0, %1, %2" : "=v"(r) : "v"(a), "v"(b));
  return r;   // low16 = bf16(a), high16 = bf16(b)
}

template<int CTRL>
__device__ __forceinline__ float dpp_add(float x) {
  // x + row_ror<CTRL>(x)  — reduction permutation within 16-lane rows
  int r = __builtin_amdgcn_update_dpp(0, __float_as_int(x), CTRL, 0xF, 0xF, false);
  return x + __int_as_float(r);
}

// ---------------------------------------------------------------------------
// Fused GEMM, raw-barrier software pipeline: global loads stay in flight
// across barriers (s_barrier + explicit lgkmcnt, NO vmcnt drain).
//   m in [0,13)  : v-proj  M=800,  Kd=1024, C = Ev  (row-major, ldc=512)
//   m in [13,77) : q-proj  M=4096, Kd=768,  C = Eq  (row-major, ldc=512)
// Tile 64x64, BK=64, 4 waves. m-grouped block decode for XCD L2 reuse.
// fp32->bf16 fused into staging (cvt_pk). LDS XOR-swizzled (row&7)<<4.
// Epilogue stores exp2(CEXP*(acc+bias)).
// ---------------------------------------------------------------------------
__global__ void __launch_bounds__(256) gemm_fused(
    const float* __restrict__ v,  const float* __restrict__ q,
    const float* __restrict__ Wv, const float* __restrict__ bv,
    const float* __restrict__ Wq, const float* __restrict__ bq,
    float* __restrict__ vpw, float* __restrict__ qpw) {
  __shared__ unsigned short As[2][64 * 64];
  __shared__ unsigned short Bs[2][64 * 64];

  const int id = blockIdx.x;
  const int m  = (id & 7) + ((id >> 6) << 3);   // m-tile index
  const int nt = (id >> 3) & 7;                 // n-tile index
  if (m >= 77) return;

  const int t = threadIdx.x;

  const float* A; const float* W; const float* bias; float* C;
  int M, Kd, m0;
  if (m < 13) { A = v; W = Wv; bias = bv; C = vpw; M = 800;  Kd = 1024; m0 = m * 64; }
  else        { A = q; W = Wq; bias = bq; C = qpw; M = 4096; Kd = 768;  m0 = (m - 13) * 64; }
  const int n0 = nt * 64;

  const int lane = t & 63;
  const int wave = t >> 6;
  const int wm   = wave >> 1;
  const int wn   = wave & 1;
  const int la   = lane & 15;
  const int lb   = lane >> 4;

  const int srow = t >> 2;
  const int skq  = (t & 3) * 16;

  int gr = m0 + srow; if (gr >= M) gr = M - 1;     // clamp; store-side guarded
  const float* Arow = A + (size_t)gr * Kd + skq;
  const float* Wrow = W + (size_t)(n0 + srow) * Kd + skq;

  f32x4 acc[2][2] = {};
  f32x4 raA[4], rbA[4], raB[4], rbB[4];

  auto loadG = [&](f32x4* ra, f32x4* rb, int s) {
    const float* ap = Arow + s * 64;
    const float* wp = Wrow + s * 64;
#pragma unroll
    for (int i = 0; i < 4; ++i) ra[i] = *(const f32x4*)&ap[i * 4];
#pragma unroll
    for (int i = 0; i < 4; ++i) rb[i] = *(const f32x4*)&wp[i * 4];
  };

  const int o0 = (srow * 128 + skq * 2)      ^ ((srow & 7) << 4);
  const int o1 = (srow * 128 + skq * 2 + 16) ^ ((srow & 7) << 4);

  auto writeL = [&](unsigned short* da, unsigned short* db,
                    const f32x4* ra, const f32x4* rb) {
    u32x4 p;
    p[0] = cvtpk(ra[0][0], ra[0][1]); p[1] = cvtpk(ra[0][2], ra[0][3]);
    p[2] = cvtpk(ra[1][0], ra[1][1]); p[3] = cvtpk(ra[1][2], ra[1][3]);
    *(u32x4*)((char*)da + o0) = p;
    p[0] = cvtpk(ra[2][0], ra[2][1]); p[1] = cvtpk(ra[2][2], ra[2][3]);
    p[2] = cvtpk(ra[3][0], ra[3][1]); p[3] = cvtpk(ra[3][2], ra[3][3]);
    *(u32x4*)((char*)da + o1) = p;
    p[0] = cvtpk(rb[0][0], rb[0][1]); p[1] = cvtpk(rb[0][2], rb[0][3]);
    p[2] = cvtpk(rb[1][0], rb[1][1]); p[3] = cvtpk(rb[1][2], rb[1][3]);
    *(u32x4*)((char*)db + o0) = p;
    p[0] = cvtpk(rb[2][0], rb[2][1]); p[1] = cvtpk(rb[2][2], rb[2][3]);
    p[2] = cvtpk(rb[3][0], rb[3][1]); p[3] = cvtpk(rb[3][2], rb[3][3]);
    *(u32x4*)((char*)db + o1) = p;
  };

  auto compute = [&](const unsigned short* sa, const unsigned short* sb) {
    bfrag af[2][2], bf[2][2];
#pragma unroll
    for (int r = 0; r < 2; ++r)
#pragma unroll
      for (int kk = 0; kk < 2; ++kk) {
        int rowa = wm * 32 + r * 16 + la;
        af[r][kk] = *(const bfrag*)((const char*)sa +
                     ((rowa * 128 + kk * 64 + lb * 16) ^ ((rowa & 7) << 4)));
        int rowb = wn * 32 + r * 16 + la;
        bf[r][kk] = *(const bfrag*)((const char*)sb +
                     ((rowb * 128 + kk * 64 + lb * 16) ^ ((rowb & 7) << 4)));
      }
#pragma unroll
    for (int kk = 0; kk < 2; ++kk)
#pragma unroll
      for (int r = 0; r < 2; ++r)
#pragma unroll
        for (int c = 0; c < 2; ++c)
          acc[r][c] = __builtin_amdgcn_mfma_f32_16x16x32_bf16(af[r][kk], bf[c][kk], acc[r][c], 0, 0, 0);
  };

  // pipeline (nsteps even: 16 / 12). Loads for step s+3 issued at step s.
  const int nsteps = Kd >> 6;
  loadG(raA, rbA, 0);
  writeL(As[0], Bs[0], raA, rbA);
  loadG(raA, rbA, 1);
  loadG(raB, rbB, 2);
  LGKM0; SCHED0; SBAR; SCHED0;
  for (int s = 0; s < nsteps; s += 2) {
    compute(As[0], Bs[0]);                         // step s
    SBAR; SCHED0;                                  // everyone done reading buf0
    writeL(As[1], Bs[1], raA, rbA);                // step s+1 (auto vmcnt wait)
    if (s + 3 < nsteps) loadG(raA, rbA, s + 3);
    LGKM0; SCHED0; SBAR; SCHED0;                   // buf1 visible
    compute(As[1], Bs[1]);                         // step s+1
    SBAR; SCHED0;                                  // everyone done reading buf1
    if (s + 2 < nsteps) {
      writeL(As[0], Bs[0], raB, rbB);              // step s+2
      if (s + 4 < nsteps) loadG(raB, rbB, s + 4);
      LGKM0; SCHED0;
    }
    SBAR; SCHED0;                                  // buf0 visible
  }

  const float CEXP = 2.885390081777927f;   // 2*log2(e)
#pragma unroll
  for (int c = 0; c < 2; ++c) {
    int col = n0 + wn * 32 + c * 16 + la;
    float bcol = bias[col];
#pragma unroll
    for (int r = 0; r < 2; ++r) {
      int mbase = m0 + wm * 32 + r * 16 + lb * 4;
#pragma unroll
      for (int e = 0; e < 4; ++e) {
        int mr = mbase + e;
        if (mr < M)
          C[(size_t)mr * 512 + col] =
              __builtin_amdgcn_exp2f((acc[r][c][e] + bcol) * CEXP);
      }
    }
  }
}

// ---------------------------------------------------------------------------
// Stage 3 (lane=h): grid (16 row-groups, 16 b), 1024 thr = 16 waves.
// Wave = one row. Lane owns h in {128j + 2*lane, +1 : j=0..3} (8 h).
// Eq row + wl live in REGISTERS (no uniform LDS reads). Ev[b] (100 KB)
// staged ONCE per block via global_load_lds; read as ds_read_b64
// (consecutive-lane pairs -> 2-way bank alias = free). ONE barrier total.
// acc[50] static-indexed; reduce = 4 DPP row_ror adds (VALU pipe) +
// predicated scatter to per-wave red[64][4] + lane=k gather/softmax.
// ---------------------------------------------------------------------------
__global__ void __launch_bounds__(1024, 4) stage3_kernel(
    const float* __restrict__ vp, const float* __restrict__ qp,
    const float* __restrict__ wl, const int* __restrict__ box_mask,
    float* __restrict__ out) {
  __shared__ float vpS[50][512];       // 102,400 B
  __shared__ float redS[16][64][4];    //  16,384 B  (per-wave private)

  const int b    = blockIdx.y;
  const int grp  = blockIdx.x;          // 0..15
  const int t    = threadIdx.x;
  const int wv   = t >> 6;              // 0..15: wave = row
  const int lane = t & 63;
  const int rowg = b * 256 + grp * 16 + wv;

  // Eq/wl register slices (fold -2 into wl)
  const float* qrow = qp + (size_t)rowg * 512;
  f32x2 eqr[4], wlr[4];
#pragma unroll
  for (int j = 0; j < 4; ++j) {
    eqr[j] = *(const f32x2*)&qrow[j * 128 + 2 * lane];
    f32x2 w = *(const f32x2*)&wl[j * 128 + 2 * lane];
    wlr[j][0] = -2.f * w[0];
    wlr[j][1] = -2.f * w[1];
  }

  // stage Ev[b] linearly: 25600 dwords / 1024 threads = 25 each
  {
    float* vf = &vpS[0][0];
    const float* src = vp + (size_t)b * 25600;
    const int ub = wv * 64;             // wave-uniform LDS base (+lane*4 by HW)
#pragma unroll
    for (int i = 0; i < 25; ++i)
      gload4(src + i * 1024 + t, vf + i * 1024 + ub);
  }
  __syncthreads();   // single barrier: vmcnt+lgkm drain, Ev visible

  float acc[50];
#pragma unroll
  for (int k = 0; k < 50; ++k) acc[k] = 0.f;

#pragma unroll
  for (int k = 0; k < 50; ++k) {
    const f32x2* vr = (const f32x2*)&vpS[k][0];
#pragma unroll
    for (int j = 0; j < 4; ++j) {
      f32x2 v2 = vr[j * 64 + lane];     // ds_read_b64, conflict-free
      acc[k] = fmaf(wlr[j][0], __builtin_amdgcn_rcpf(fmaf(v2[0], eqr[j][0], 1.f)), acc[k]);
      acc[k] = fmaf(wlr[j][1], __builtin_amdgcn_rcpf(fmaf(v2[1], eqr[j][1], 1.f)), acc[k]);
    }
  }

  // intra-16-lane reduce (DPP row_ror: 8,4,2,1) + predicated scatter
  const int g  = lane >> 4;             // 16-lane group 0..3
  const int li = lane & 15;
#pragma unroll
  for (int k = 0; k < 50; ++k) {
    float s = acc[k];
    s = dpp_add<0x128>(s);              // ror:8
    s = dpp_add<0x124>(s);              // ror:4
    s = dpp_add<0x122>(s);              // ror:2
    s = dpp_add<0x121>(s);              // ror:1  -> group total in every lane
    if (li == (k & 15)) redS[wv][k][g] = s;   // 4 writer lanes (one per g)
  }

  // gather (same wave; ds ops complete in order -> no barrier needed)
  const int k = lane;
  f32x4 rv = *(const f32x4*)&redS[wv][k][0];
  float logit = (rv[0] + rv[1]) + (rv[2] + rv[3]);

  // masked softmax over lanes 0..49
  int   msk = (k < 50) ? box_mask[b * 50 + k] : 0;
  float l   = (k < 50 && msk > 0) ? logit : -1e9f;

  float mx = l;
#pragma unroll
  for (int off = 32; off; off >>= 1) mx = fmaxf(mx, __shfl_xor(mx, off));
  float e = (k < 50) ? __builtin_amdgcn_exp2f((l - mx) * 1.4426950408889634f) : 0.f;
  float s = e;
#pragma unroll
  for (int off = 32; off; off >>= 1) s += __shfl_xor(s, off);

  if (k < 50) out[(size_t)rowg * 50 + k] = e / s;
}

// ---------------------------------------------------------------------------
// launch
// ---------------------------------------------------------------------------
extern "C" void kernel_launch(void* const* d_in, const int* in_sizes, int n_in,
                              void* d_out, int out_size, void* d_ws, size_t ws_size,
                              hipStream_t stream) {
  const float* v        = (const float*)d_in[0];
  const float* q        = (const float*)d_in[1];
  const int*   box_mask = (const int*)d_in[2];
  // d_in[3] = tags_attention (unused by reference)
  const float* Wv       = (const float*)d_in[4];
  const float* bv       = (const float*)d_in[5];
  const float* Wq       = (const float*)d_in[6];
  const float* bq       = (const float*)d_in[7];
  const float* Wl       = (const float*)d_in[8];
  // d_in[9] = bl (softmax-invariant, and zero)
  float* out = (float*)d_out;

  char* ws = (char*)d_ws;
  float* vpw = (float*)(ws);             // 800*512*4  = 1,638,400 B  (Ev)
  float* qpw = (float*)(ws + 1638400);   // 4096*512*4 = 8,388,608 B  (Eq)

  gemm_fused<<<dim3(640),     256,  0, stream>>>(v, q, Wv, bv, Wq, bq, vpw, qpw);
  stage3_kernel<<<dim3(16, 16), 1024, 0, stream>>>(vpw, qpw, Wl, box_mask, out);
}

// Round 8
// 93.205 us; speedup vs baseline: 1.8428x; 1.8428x over previous
//
#include <hip/hip_runtime.h>
#include <hip/hip_bf16.h>
#include <cstddef>

// ---------------------------------------------------------------------------
// B=16, N=4, S=64, K=50, VD=1024, QD=768, H=512; ROWS = B*N*S = 4096
//   Ev[k_glob][h] = exp2(CEXP*(v[b,k,:] .Wv[h,:] + bv[h]))   (row-major)
//   Eq[row][h]    = exp2(CEXP*(q[row,:] .Wq[h,:] + bq[h]))
//   logit[row][k] = sum_h (-2*wl[h]) * rcp(Ev[k][h]*Eq[row][h] + 1)
//     (tanh(x) = 1 - 2/(e^{2x}+1); exp2 factorized into the projection
//      spaces; k-uniform sum_h wl dropped: softmax-invariant; CEXP=2*log2e)
//   out = masked softmax over k (50 boxes)
// ---------------------------------------------------------------------------

typedef __attribute__((ext_vector_type(2))) float        f32x2;
typedef __attribute__((ext_vector_type(4))) float        f32x4;
typedef __attribute__((ext_vector_type(8))) short        bfrag;   // 8 bf16
typedef __attribute__((ext_vector_type(4))) unsigned int u32x4;

#define LGKM0  asm volatile("s_waitcnt lgkmcnt(0)" ::: "memory")
#define SBAR   __builtin_amdgcn_s_barrier()
#define SCHED0 __builtin_amdgcn_sched_barrier(0)

__device__ __forceinline__ void gload4(const float* g, float* l) {
  __builtin_amdgcn_global_load_lds((const __attribute__((address_space(1))) void*)g,
                                   (__attribute__((address_space(3))) void*)l, 4, 0, 0);
}

__device__ __forceinline__ unsigned int cvtpk(float a, float b) {
  unsigned int r;
  asm("v_cvt_pk_bf16_f32 %0, %1, %2" : "=v"(r) : "v"(a), "v"(b));
  return r;   // low16 = bf16(a), high16 = bf16(b)
}

template<int CTRL>
__device__ __forceinline__ float dpp_add(float x) {
  // x + row_ror<CTRL>(x)  — reduction permutation within 16-lane rows
  int r = __builtin_amdgcn_update_dpp(0, __float_as_int(x), CTRL, 0xF, 0xF, false);
  return x + __int_as_float(r);
}

// ---------------------------------------------------------------------------
// Fused GEMM, raw-barrier software pipeline: global loads stay in flight
// across barriers (s_barrier + explicit lgkmcnt, NO vmcnt drain).
//   m in [0,13)  : v-proj  M=800,  Kd=1024, C = Ev  (row-major, ldc=512)
//   m in [13,77) : q-proj  M=4096, Kd=768,  C = Eq  (row-major, ldc=512)
// Tile 64x64, BK=64, 4 waves. m-grouped block decode for XCD L2 reuse.
// fp32->bf16 fused into staging (cvt_pk). LDS XOR-swizzled (row&7)<<4.
// Epilogue stores exp2(CEXP*(acc+bias)).
// ---------------------------------------------------------------------------
__global__ void __launch_bounds__(256) gemm_fused(
    const float* __restrict__ v,  const float* __restrict__ q,
    const float* __restrict__ Wv, const float* __restrict__ bv,
    const float* __restrict__ Wq, const float* __restrict__ bq,
    float* __restrict__ vpw, float* __restrict__ qpw) {
  __shared__ unsigned short As[2][64 * 64];
  __shared__ unsigned short Bs[2][64 * 64];

  const int id = blockIdx.x;
  const int m  = (id & 7) + ((id >> 6) << 3);   // m-tile index
  const int nt = (id >> 3) & 7;                 // n-tile index
  if (m >= 77) return;

  const int t = threadIdx.x;

  const float* A; const float* W; const float* bias; float* C;
  int M, Kd, m0;
  if (m < 13) { A = v; W = Wv; bias = bv; C = vpw; M = 800;  Kd = 1024; m0 = m * 64; }
  else        { A = q; W = Wq; bias = bq; C = qpw; M = 4096; Kd = 768;  m0 = (m - 13) * 64; }
  const int n0 = nt * 64;

  const int lane = t & 63;
  const int wave = t >> 6;
  const int wm   = wave >> 1;
  const int wn   = wave & 1;
  const int la   = lane & 15;
  const int lb   = lane >> 4;

  const int srow = t >> 2;
  const int skq  = (t & 3) * 16;

  int gr = m0 + srow; if (gr >= M) gr = M - 1;     // clamp; store-side guarded
  const float* Arow = A + (size_t)gr * Kd + skq;
  const float* Wrow = W + (size_t)(n0 + srow) * Kd + skq;

  f32x4 acc[2][2] = {};
  f32x4 raA[4], rbA[4], raB[4], rbB[4];

  auto loadG = [&](f32x4* ra, f32x4* rb, int s) {
    const float* ap = Arow + s * 64;
    const float* wp = Wrow + s * 64;
#pragma unroll
    for (int i = 0; i < 4; ++i) ra[i] = *(const f32x4*)&ap[i * 4];
#pragma unroll
    for (int i = 0; i < 4; ++i) rb[i] = *(const f32x4*)&wp[i * 4];
  };

  const int o0 = (srow * 128 + skq * 2)      ^ ((srow & 7) << 4);
  const int o1 = (srow * 128 + skq * 2 + 16) ^ ((srow & 7) << 4);

  auto writeL = [&](unsigned short* da, unsigned short* db,
                    const f32x4* ra, const f32x4* rb) {
    u32x4 p;
    p[0] = cvtpk(ra[0][0], ra[0][1]); p[1] = cvtpk(ra[0][2], ra[0][3]);
    p[2] = cvtpk(ra[1][0], ra[1][1]); p[3] = cvtpk(ra[1][2], ra[1][3]);
    *(u32x4*)((char*)da + o0) = p;
    p[0] = cvtpk(ra[2][0], ra[2][1]); p[1] = cvtpk(ra[2][2], ra[2][3]);
    p[2] = cvtpk(ra[3][0], ra[3][1]); p[3] = cvtpk(ra[3][2], ra[3][3]);
    *(u32x4*)((char*)da + o1) = p;
    p[0] = cvtpk(rb[0][0], rb[0][1]); p[1] = cvtpk(rb[0][2], rb[0][3]);
    p[2] = cvtpk(rb[1][0], rb[1][1]); p[3] = cvtpk(rb[1][2], rb[1][3]);
    *(u32x4*)((char*)db + o0) = p;
    p[0] = cvtpk(rb[2][0], rb[2][1]); p[1] = cvtpk(rb[2][2], rb[2][3]);
    p[2] = cvtpk(rb[3][0], rb[3][1]); p[3] = cvtpk(rb[3][2], rb[3][3]);
    *(u32x4*)((char*)db + o1) = p;
  };

  auto compute = [&](const unsigned short* sa, const unsigned short* sb) {
    bfrag af[2][2], bf[2][2];
#pragma unroll
    for (int r = 0; r < 2; ++r)
#pragma unroll
      for (int kk = 0; kk < 2; ++kk) {
        int rowa = wm * 32 + r * 16 + la;
        af[r][kk] = *(const bfrag*)((const char*)sa +
                     ((rowa * 128 + kk * 64 + lb * 16) ^ ((rowa & 7) << 4)));
        int rowb = wn * 32 + r * 16 + la;
        bf[r][kk] = *(const bfrag*)((const char*)sb +
                     ((rowb * 128 + kk * 64 + lb * 16) ^ ((rowb & 7) << 4)));
      }
#pragma unroll
    for (int kk = 0; kk < 2; ++kk)
#pragma unroll
      for (int r = 0; r < 2; ++r)
#pragma unroll
        for (int c = 0; c < 2; ++c)
          acc[r][c] = __builtin_amdgcn_mfma_f32_16x16x32_bf16(af[r][kk], bf[c][kk], acc[r][c], 0, 0, 0);
  };

  // pipeline (nsteps even: 16 / 12). Loads for step s+3 issued at step s.
  const int nsteps = Kd >> 6;
  loadG(raA, rbA, 0);
  writeL(As[0], Bs[0], raA, rbA);
  loadG(raA, rbA, 1);
  loadG(raB, rbB, 2);
  LGKM0; SCHED0; SBAR; SCHED0;
  for (int s = 0; s < nsteps; s += 2) {
    compute(As[0], Bs[0]);                         // step s
    SBAR; SCHED0;                                  // everyone done reading buf0
    writeL(As[1], Bs[1], raA, rbA);                // step s+1 (auto vmcnt wait)
    if (s + 3 < nsteps) loadG(raA, rbA, s + 3);
    LGKM0; SCHED0; SBAR; SCHED0;                   // buf1 visible
    compute(As[1], Bs[1]);                         // step s+1
    SBAR; SCHED0;                                  // everyone done reading buf1
    if (s + 2 < nsteps) {
      writeL(As[0], Bs[0], raB, rbB);              // step s+2
      if (s + 4 < nsteps) loadG(raB, rbB, s + 4);
      LGKM0; SCHED0;
    }
    SBAR; SCHED0;                                  // buf0 visible
  }

  const float CEXP = 2.885390081777927f;   // 2*log2(e)
#pragma unroll
  for (int c = 0; c < 2; ++c) {
    int col = n0 + wn * 32 + c * 16 + la;
    float bcol = bias[col];
#pragma unroll
    for (int r = 0; r < 2; ++r) {
      int mbase = m0 + wm * 32 + r * 16 + lb * 4;
#pragma unroll
      for (int e = 0; e < 4; ++e) {
        int mr = mbase + e;
        if (mr < M)
          C[(size_t)mr * 512 + col] =
              __builtin_amdgcn_exp2f((acc[r][c][e] + bcol) * CEXP);
      }
    }
  }
}

// ---------------------------------------------------------------------------
// Stage 3 (lane=h, spill-free): grid (16 row-groups, 16 b), 1024 thr = 16 wv.
// Wave = one row. Lane owns h in {128j + 2*lane, +1 : j=0..3} (8 h).
// Eq row + wl live in REGISTERS. Ev[b] (100 KB) staged ONCE per block via
// global_load_lds; read as ds_read_b64 (2-way alias = free). ONE barrier.
// k processed in 2 chunks of 25 accumulators -> live set ~55 VGPR, no spill
// (round-7 lesson: acc[50] spilled -> 161 MB scratch traffic).
// Reduce = 4 DPP row_ror adds + predicated scatter to per-wave red[64][4],
// then lane=k gather + masked softmax.
// ---------------------------------------------------------------------------
__global__ void __launch_bounds__(1024, 4) stage3_kernel(
    const float* __restrict__ vp, const float* __restrict__ qp,
    const float* __restrict__ wl, const int* __restrict__ box_mask,
    float* __restrict__ out) {
  __shared__ float vpS[50][512];       // 102,400 B
  __shared__ float redS[16][64][4];    //  16,384 B  (per-wave private)

  const int b    = blockIdx.y;
  const int grp  = blockIdx.x;          // 0..15
  const int t    = threadIdx.x;
  const int wv   = t >> 6;              // 0..15: wave = row
  const int lane = t & 63;
  const int rowg = b * 256 + grp * 16 + wv;

  // Eq/wl register slices (fold -2 into wl)
  const float* qrow = qp + (size_t)rowg * 512;
  f32x2 eqr[4], wlr[4];
#pragma unroll
  for (int j = 0; j < 4; ++j) {
    eqr[j] = *(const f32x2*)&qrow[j * 128 + 2 * lane];
    f32x2 w = *(const f32x2*)&wl[j * 128 + 2 * lane];
    wlr[j][0] = -2.f * w[0];
    wlr[j][1] = -2.f * w[1];
  }

  // stage Ev[b] linearly: 25600 dwords / 1024 threads = 25 each
  {
    float* vf = &vpS[0][0];
    const float* src = vp + (size_t)b * 25600;
    const int ub = wv * 64;             // wave-uniform LDS base (+lane*4 by HW)
#pragma unroll
    for (int i = 0; i < 25; ++i)
      gload4(src + i * 1024 + t, vf + i * 1024 + ub);
  }
  __syncthreads();   // single barrier: vmcnt+lgkm drain, Ev visible

  const int g  = lane >> 4;             // 16-lane group 0..3
  const int li = lane & 15;

#pragma unroll 1
  for (int kc = 0; kc < 2; ++kc) {      // rolled: one 25-wide body, no spill
    float acc[25];
#pragma unroll
    for (int i = 0; i < 25; ++i) acc[i] = 0.f;

#pragma unroll
    for (int i = 0; i < 25; ++i) {
      const f32x2* vr = (const f32x2*)&vpS[kc * 25 + i][0];
#pragma unroll
      for (int j = 0; j < 4; ++j) {
        f32x2 v2 = vr[j * 64 + lane];   // ds_read_b64, conflict-free
        acc[i] = fmaf(wlr[j][0], __builtin_amdgcn_rcpf(fmaf(v2[0], eqr[j][0], 1.f)), acc[i]);
        acc[i] = fmaf(wlr[j][1], __builtin_amdgcn_rcpf(fmaf(v2[1], eqr[j][1], 1.f)), acc[i]);
      }
    }

    // intra-16-lane reduce (DPP row_ror: 8,4,2,1) + predicated scatter
#pragma unroll
    for (int i = 0; i < 25; ++i) {
      int k = kc * 25 + i;
      float s = acc[i];
      s = dpp_add<0x128>(s);            // ror:8
      s = dpp_add<0x124>(s);            // ror:4
      s = dpp_add<0x122>(s);            // ror:2
      s = dpp_add<0x121>(s);            // ror:1  -> group total in every lane
      if (li == (k & 15)) redS[wv][k][g] = s;   // 4 writer lanes (one per g)
    }
  }

  // gather (same wave; ds ops complete in order -> no barrier needed)
  const int k = lane;
  f32x4 rv = *(const f32x4*)&redS[wv][k][0];
  float logit = (rv[0] + rv[1]) + (rv[2] + rv[3]);

  // masked softmax over lanes 0..49
  int   msk = (k < 50) ? box_mask[b * 50 + k] : 0;
  float l   = (k < 50 && msk > 0) ? logit : -1e9f;

  float mx = l;
#pragma unroll
  for (int off = 32; off; off >>= 1) mx = fmaxf(mx, __shfl_xor(mx, off));
  float e = (k < 50) ? __builtin_amdgcn_exp2f((l - mx) * 1.4426950408889634f) : 0.f;
  float s = e;
#pragma unroll
  for (int off = 32; off; off >>= 1) s += __shfl_xor(s, off);

  if (k < 50) out[(size_t)rowg * 50 + k] = e / s;
}

// ---------------------------------------------------------------------------
// launch
// ---------------------------------------------------------------------------
extern "C" void kernel_launch(void* const* d_in, const int* in_sizes, int n_in,
                              void* d_out, int out_size, void* d_ws, size_t ws_size,
                              hipStream_t stream) {
  const float* v        = (const float*)d_in[0];
  const float* q        = (const float*)d_in[1];
  const int*   box_mask = (const int*)d_in[2];
  // d_in[3] = tags_attention (unused by reference)
  const float* Wv       = (const float*)d_in[4];
  const float* bv       = (const float*)d_in[5];
  const float* Wq       = (const float*)d_in[6];
  const float* bq       = (const float*)d_in[7];
  const float* Wl       = (const float*)d_in[8];
  // d_in[9] = bl (softmax-invariant, and zero)
  float* out = (float*)d_out;

  char* ws = (char*)d_ws;
  float* vpw = (float*)(ws);             // 800*512*4  = 1,638,400 B  (Ev)
  float* qpw = (float*)(ws + 1638400);   // 4096*512*4 = 8,388,608 B  (Eq)

  gemm_fused<<<dim3(640),     256,  0, stream>>>(v, q, Wv, bv, Wq, bq, vpw, qpw);
  stage3_kernel<<<dim3(16, 16), 1024, 0, stream>>>(vpw, qpw, Wl, box_mask, out);
}

// Round 9
// 49.519 us; speedup vs baseline: 3.4686x; 1.8822x over previous
//
#include <hip/hip_runtime.h>
#include <hip/hip_bf16.h>
#include <cstddef>

// ---------------------------------------------------------------------------
// B=16, N=4, S=64, K=50, VD=1024, QD=768, H=512; ROWS = B*N*S = 4096
//   Ev[k_glob][h] = exp2(CEXP*(v[b,k,:] .Wv[h,:] + bv[h]))   (row-major)
//   Eq[row][h]    = exp2(CEXP*(q[row,:] .Wq[h,:] + bq[h]))
//   logit[row][k] = sum_h (-2*wl[h]) * rcp(Ev[k][h]*Eq[row][h] + 1)
//     (tanh(x) = 1 - 2/(e^{2x}+1); exp2 factorized into the projection
//      spaces; k-uniform sum_h wl dropped: softmax-invariant; CEXP=2*log2e)
//   out = masked softmax over k (50 boxes)
// ---------------------------------------------------------------------------

typedef __attribute__((ext_vector_type(2))) float        f32x2;
typedef __attribute__((ext_vector_type(4))) float        f32x4;
typedef __attribute__((ext_vector_type(8))) short        bfrag;   // 8 bf16
typedef __attribute__((ext_vector_type(4))) unsigned int u32x4;

#define LGKM0  asm volatile("s_waitcnt lgkmcnt(0)" ::: "memory")
#define SBAR   __builtin_amdgcn_s_barrier()
#define SCHED0 __builtin_amdgcn_sched_barrier(0)

__device__ __forceinline__ void gload4(const float* g, float* l) {
  __builtin_amdgcn_global_load_lds((const __attribute__((address_space(1))) void*)g,
                                   (__attribute__((address_space(3))) void*)l, 4, 0, 0);
}

__device__ __forceinline__ unsigned int cvtpk(float a, float b) {
  unsigned int r;
  asm("v_cvt_pk_bf16_f32 %0, %1, %2" : "=v"(r) : "v"(a), "v"(b));
  return r;   // low16 = bf16(a), high16 = bf16(b)
}

template<int CTRL>
__device__ __forceinline__ float dpp_add(float x) {
  // x + row_ror<CTRL>(x)  — reduction permutation within 16-lane rows
  int r = __builtin_amdgcn_update_dpp(0, __float_as_int(x), CTRL, 0xF, 0xF, false);
  return x + __int_as_float(r);
}

// ---------------------------------------------------------------------------
// Fused GEMM, raw-barrier software pipeline: global loads stay in flight
// across barriers (s_barrier + explicit lgkmcnt, NO vmcnt drain).
//   m in [0,13)  : v-proj  M=800,  Kd=1024, C = Ev  (row-major, ldc=512)
//   m in [13,77) : q-proj  M=4096, Kd=768,  C = Eq  (row-major, ldc=512)
// Tile 64x64, BK=64, 4 waves. m-grouped block decode for XCD L2 reuse.
// fp32->bf16 fused into staging (cvt_pk). LDS XOR-swizzled (row&7)<<4.
// Epilogue stores exp2(CEXP*(acc+bias)).
// ---------------------------------------------------------------------------
__global__ void __launch_bounds__(256) gemm_fused(
    const float* __restrict__ v,  const float* __restrict__ q,
    const float* __restrict__ Wv, const float* __restrict__ bv,
    const float* __restrict__ Wq, const float* __restrict__ bq,
    float* __restrict__ vpw, float* __restrict__ qpw) {
  __shared__ unsigned short As[2][64 * 64];
  __shared__ unsigned short Bs[2][64 * 64];

  const int id = blockIdx.x;
  const int m  = (id & 7) + ((id >> 6) << 3);   // m-tile index
  const int nt = (id >> 3) & 7;                 // n-tile index
  if (m >= 77) return;

  const int t = threadIdx.x;

  const float* A; const float* W; const float* bias; float* C;
  int M, Kd, m0;
  if (m < 13) { A = v; W = Wv; bias = bv; C = vpw; M = 800;  Kd = 1024; m0 = m * 64; }
  else        { A = q; W = Wq; bias = bq; C = qpw; M = 4096; Kd = 768;  m0 = (m - 13) * 64; }
  const int n0 = nt * 64;

  const int lane = t & 63;
  const int wave = t >> 6;
  const int wm   = wave >> 1;
  const int wn   = wave & 1;
  const int la   = lane & 15;
  const int lb   = lane >> 4;

  const int srow = t >> 2;
  const int skq  = (t & 3) * 16;

  int gr = m0 + srow; if (gr >= M) gr = M - 1;     // clamp; store-side guarded
  const float* Arow = A + (size_t)gr * Kd + skq;
  const float* Wrow = W + (size_t)(n0 + srow) * Kd + skq;

  f32x4 acc[2][2] = {};
  f32x4 raA[4], rbA[4], raB[4], rbB[4];

  auto loadG = [&](f32x4* ra, f32x4* rb, int s) {
    const float* ap = Arow + s * 64;
    const float* wp = Wrow + s * 64;
#pragma unroll
    for (int i = 0; i < 4; ++i) ra[i] = *(const f32x4*)&ap[i * 4];
#pragma unroll
    for (int i = 0; i < 4; ++i) rb[i] = *(const f32x4*)&wp[i * 4];
  };

  const int o0 = (srow * 128 + skq * 2)      ^ ((srow & 7) << 4);
  const int o1 = (srow * 128 + skq * 2 + 16) ^ ((srow & 7) << 4);

  auto writeL = [&](unsigned short* da, unsigned short* db,
                    const f32x4* ra, const f32x4* rb) {
    u32x4 p;
    p[0] = cvtpk(ra[0][0], ra[0][1]); p[1] = cvtpk(ra[0][2], ra[0][3]);
    p[2] = cvtpk(ra[1][0], ra[1][1]); p[3] = cvtpk(ra[1][2], ra[1][3]);
    *(u32x4*)((char*)da + o0) = p;
    p[0] = cvtpk(ra[2][0], ra[2][1]); p[1] = cvtpk(ra[2][2], ra[2][3]);
    p[2] = cvtpk(ra[3][0], ra[3][1]); p[3] = cvtpk(ra[3][2], ra[3][3]);
    *(u32x4*)((char*)da + o1) = p;
    p[0] = cvtpk(rb[0][0], rb[0][1]); p[1] = cvtpk(rb[0][2], rb[0][3]);
    p[2] = cvtpk(rb[1][0], rb[1][1]); p[3] = cvtpk(rb[1][2], rb[1][3]);
    *(u32x4*)((char*)db + o0) = p;
    p[0] = cvtpk(rb[2][0], rb[2][1]); p[1] = cvtpk(rb[2][2], rb[2][3]);
    p[2] = cvtpk(rb[3][0], rb[3][1]); p[3] = cvtpk(rb[3][2], rb[3][3]);
    *(u32x4*)((char*)db + o1) = p;
  };

  auto compute = [&](const unsigned short* sa, const unsigned short* sb) {
    bfrag af[2][2], bf[2][2];
#pragma unroll
    for (int r = 0; r < 2; ++r)
#pragma unroll
      for (int kk = 0; kk < 2; ++kk) {
        int rowa = wm * 32 + r * 16 + la;
        af[r][kk] = *(const bfrag*)((const char*)sa +
                     ((rowa * 128 + kk * 64 + lb * 16) ^ ((rowa & 7) << 4)));
        int rowb = wn * 32 + r * 16 + la;
        bf[r][kk] = *(const bfrag*)((const char*)sb +
                     ((rowb * 128 + kk * 64 + lb * 16) ^ ((rowb & 7) << 4)));
      }
#pragma unroll
    for (int kk = 0; kk < 2; ++kk)
#pragma unroll
      for (int r = 0; r < 2; ++r)
#pragma unroll
        for (int c = 0; c < 2; ++c)
          acc[r][c] = __builtin_amdgcn_mfma_f32_16x16x32_bf16(af[r][kk], bf[c][kk], acc[r][c], 0, 0, 0);
  };

  // pipeline (nsteps even: 16 / 12). Loads for step s+3 issued at step s.
  const int nsteps = Kd >> 6;
  loadG(raA, rbA, 0);
  writeL(As[0], Bs[0], raA, rbA);
  loadG(raA, rbA, 1);
  loadG(raB, rbB, 2);
  LGKM0; SCHED0; SBAR; SCHED0;
  for (int s = 0; s < nsteps; s += 2) {
    compute(As[0], Bs[0]);                         // step s
    SBAR; SCHED0;                                  // everyone done reading buf0
    writeL(As[1], Bs[1], raA, rbA);                // step s+1 (auto vmcnt wait)
    if (s + 3 < nsteps) loadG(raA, rbA, s + 3);
    LGKM0; SCHED0; SBAR; SCHED0;                   // buf1 visible
    compute(As[1], Bs[1]);                         // step s+1
    SBAR; SCHED0;                                  // everyone done reading buf1
    if (s + 2 < nsteps) {
      writeL(As[0], Bs[0], raB, rbB);              // step s+2
      if (s + 4 < nsteps) loadG(raB, rbB, s + 4);
      LGKM0; SCHED0;
    }
    SBAR; SCHED0;                                  // buf0 visible
  }

  const float CEXP = 2.885390081777927f;   // 2*log2(e)
#pragma unroll
  for (int c = 0; c < 2; ++c) {
    int col = n0 + wn * 32 + c * 16 + la;
    float bcol = bias[col];
#pragma unroll
    for (int r = 0; r < 2; ++r) {
      int mbase = m0 + wm * 32 + r * 16 + lb * 4;
#pragma unroll
      for (int e = 0; e < 4; ++e) {
        int mr = mbase + e;
        if (mr < M)
          C[(size_t)mr * 512 + col] =
              __builtin_amdgcn_exp2f((acc[r][c][e] + bcol) * CEXP);
      }
    }
  }
}

// ---------------------------------------------------------------------------
// Stage 3 (lane=h, spill-free): grid (16 row-groups, 16 b), 1024 thr = 16 wv.
// amdgpu_waves_per_eu(4,4) pins the occupancy target at exactly 4 waves/EU
// (the LDS-forced 1 block/CU) -> 128-VGPR budget; round-8's default heuristic
// targeted 8 waves/EU -> 64 VGPR -> acc spill -> 290 MB scratch traffic.
// Wave = one row. Lane owns h in {128j + 2*lane, +1 : j=0..3} (8 h).
// Eq row + wl in REGISTERS. Ev[b] (100 KB) staged ONCE via global_load_lds;
// read as ds_read_b64 (2-way alias = free). ONE barrier.
// k in 5 chunks of 10 accumulators (live ~50 VGPR even at a 64 budget).
// Reduce = 4 DPP row_ror adds + predicated scatter to per-wave red[64][4],
// then lane=k gather + masked softmax.
// ---------------------------------------------------------------------------
__global__ void
__attribute__((amdgpu_flat_work_group_size(1024, 1024), amdgpu_waves_per_eu(4, 4)))
stage3_kernel(
    const float* __restrict__ vp, const float* __restrict__ qp,
    const float* __restrict__ wl, const int* __restrict__ box_mask,
    float* __restrict__ out) {
  __shared__ float vpS[50][512];       // 102,400 B
  __shared__ float redS[16][64][4];    //  16,384 B  (per-wave private)

  const int b    = blockIdx.y;
  const int grp  = blockIdx.x;          // 0..15
  const int t    = threadIdx.x;
  const int wv   = t >> 6;              // 0..15: wave = row
  const int lane = t & 63;
  const int rowg = b * 256 + grp * 16 + wv;

  // Eq/wl register slices (fold -2 into wl)
  const float* qrow = qp + (size_t)rowg * 512;
  f32x2 eqr[4], wlr[4];
#pragma unroll
  for (int j = 0; j < 4; ++j) {
    eqr[j] = *(const f32x2*)&qrow[j * 128 + 2 * lane];
    f32x2 w = *(const f32x2*)&wl[j * 128 + 2 * lane];
    wlr[j][0] = -2.f * w[0];
    wlr[j][1] = -2.f * w[1];
  }

  // stage Ev[b] linearly: 25600 dwords / 1024 threads = 25 each
  {
    float* vf = &vpS[0][0];
    const float* src = vp + (size_t)b * 25600;
    const int ub = wv * 64;             // wave-uniform LDS base (+lane*4 by HW)
#pragma unroll
    for (int i = 0; i < 25; ++i)
      gload4(src + i * 1024 + t, vf + i * 1024 + ub);
  }
  __syncthreads();   // single barrier: vmcnt+lgkm drain, Ev visible

  const int g  = lane >> 4;             // 16-lane group 0..3
  const int li = lane & 15;

#pragma unroll 1
  for (int kc = 0; kc < 5; ++kc) {      // rolled: one 10-wide body, no spill
    float acc[10];
#pragma unroll
    for (int i = 0; i < 10; ++i) acc[i] = 0.f;

#pragma unroll
    for (int i = 0; i < 10; ++i) {
      const f32x2* vr = (const f32x2*)&vpS[kc * 10 + i][0];
#pragma unroll
      for (int j = 0; j < 4; ++j) {
        f32x2 v2 = vr[j * 64 + lane];   // ds_read_b64, conflict-free
        acc[i] = fmaf(wlr[j][0], __builtin_amdgcn_rcpf(fmaf(v2[0], eqr[j][0], 1.f)), acc[i]);
        acc[i] = fmaf(wlr[j][1], __builtin_amdgcn_rcpf(fmaf(v2[1], eqr[j][1], 1.f)), acc[i]);
      }
    }

    // intra-16-lane reduce (DPP row_ror: 8,4,2,1) + predicated scatter
#pragma unroll
    for (int i = 0; i < 10; ++i) {
      int k = kc * 10 + i;
      float s = acc[i];
      s = dpp_add<0x128>(s);            // ror:8
      s = dpp_add<0x124>(s);            // ror:4
      s = dpp_add<0x122>(s);            // ror:2
      s = dpp_add<0x121>(s);            // ror:1  -> group total in every lane
      if (li == (k & 15)) redS[wv][k][g] = s;   // 4 writer lanes (one per g)
    }
  }

  // gather (same wave; ds ops complete in order -> no barrier needed)
  const int k = lane;
  f32x4 rv = *(const f32x4*)&redS[wv][k][0];
  float logit = (rv[0] + rv[1]) + (rv[2] + rv[3]);

  // masked softmax over lanes 0..49
  int   msk = (k < 50) ? box_mask[b * 50 + k] : 0;
  float l   = (k < 50 && msk > 0) ? logit : -1e9f;

  float mx = l;
#pragma unroll
  for (int off = 32; off; off >>= 1) mx = fmaxf(mx, __shfl_xor(mx, off));
  float e = (k < 50) ? __builtin_amdgcn_exp2f((l - mx) * 1.4426950408889634f) : 0.f;
  float s = e;
#pragma unroll
  for (int off = 32; off; off >>= 1) s += __shfl_xor(s, off);

  if (k < 50) out[(size_t)rowg * 50 + k] = e / s;
}

// ---------------------------------------------------------------------------
// launch
// ---------------------------------------------------------------------------
extern "C" void kernel_launch(void* const* d_in, const int* in_sizes, int n_in,
                              void* d_out, int out_size, void* d_ws, size_t ws_size,
                              hipStream_t stream) {
  const float* v        = (const float*)d_in[0];
  const float* q        = (const float*)d_in[1];
  const int*   box_mask = (const int*)d_in[2];
  // d_in[3] = tags_attention (unused by reference)
  const float* Wv       = (const float*)d_in[4];
  const float* bv       = (const float*)d_in[5];
  const float* Wq       = (const float*)d_in[6];
  const float* bq       = (const float*)d_in[7];
  const float* Wl       = (const float*)d_in[8];
  // d_in[9] = bl (softmax-invariant, and zero)
  float* out = (float*)d_out;

  char* ws = (char*)d_ws;
  float* vpw = (float*)(ws);             // 800*512*4  = 1,638,400 B  (Ev)
  float* qpw = (float*)(ws + 1638400);   // 4096*512*4 = 8,388,608 B  (Eq)

  gemm_fused<<<dim3(640),     256,  0, stream>>>(v, q, Wv, bv, Wq, bq, vpw, qpw);
  stage3_kernel<<<dim3(16, 16), 1024, 0, stream>>>(vpw, qpw, Wl, box_mask, out);
}